// Round 12
// baseline (239.595 us; speedup 1.0000x reference)
//
#include <hip/hip_runtime.h>
#include <hip/hip_fp16.h>
#include <math.h>

#define N_NODES 50000
#define N_EDGES 800000
#define IN_FEATS 128
#define N_HIDDEN 64
#define OUT_FEATS 40
#define DIM 8
#define GT_TILES ((N_NODES + 63) / 64)            // 782 gemm tiles
#define HIST_NB ((N_EDGES / 4 + 255) / 256)       // 782 hist blocks
#define GAUSS_NB (N_EDGES / 256)                  // 3125 gauss blocks, 1 edge/thread
#define FILLQ_NB ((N_EDGES / 4 + 255) / 256)      // 782 fill blocks, 4 edges/thread
#define SCAN_NB ((N_NODES + 255) / 256)           // 196 scan blocks
#define CNT_STRIDE 4                               // counts padded to 16B/counter
#define WCOLS 48                                   // W12 cols padded 40 -> 48
#define W12_NB ((WCOLS * IN_FEATS) / 256)          // 24 blocks

typedef _Float16 half8 __attribute__((ext_vector_type(8)));
typedef float floatx4 __attribute__((ext_vector_type(4)));

// ---------------- wave-wide inclusive scan (64 lanes) ----------------
__device__ __forceinline__ int wave_incl_scan(int x, int lane) {
#pragma unroll
    for (int off = 1; off < 64; off <<= 1) {
        int v = __shfl_up(x, off, 64);
        if (lane >= off) x += v;
    }
    return x;
}

// ============================================================================
// K0: W12 = W1 @ W2 (fp16, transposed [48][128] zero-padded) + cvec = b1 @ W2.
// Also zeroes padded counts + lookback partials (replaces hipMemsetAsync).
// ============================================================================
__global__ __launch_bounds__(256) void w12_kernel(const float* __restrict__ W1,
                                                  const float* __restrict__ W2,
                                                  const float* __restrict__ b1,
                                                  __half* __restrict__ w12T,
                                                  float* __restrict__ cvec,
                                                  int* __restrict__ counts,
                                                  int* __restrict__ partials) {
    const int gtid = blockIdx.x * 256 + threadIdx.x;   // < 6144

    for (int i = gtid; i < (N_NODES * CNT_STRIDE) / 4; i += W12_NB * 256)
        ((int4*)counts)[i] = make_int4(0, 0, 0, 0);
    if (gtid < 256) partials[gtid] = 0;

    const int c = gtid >> 7;             // 0..47 (out col)
    const int i = gtid & 127;            // input feat
    float s = 0.f;
    if (c < OUT_FEATS) {
#pragma unroll 8
        for (int k = 0; k < N_HIDDEN; ++k)
            s += W1[i * N_HIDDEN + k] * W2[k * OUT_FEATS + c];
    }
    w12T[gtid] = __float2half(s);        // w12T[c][i]
    if (gtid < OUT_FEATS) {
        float t = 0.f;
        for (int k = 0; k < N_HIDDEN; ++k)
            t += b1[k] * W2[k * OUT_FEATS + gtid];
        cvec[gtid] = t;
    }
}

// ============================================================================
// K1: MERGED hist + gauss + Y-gemm. Hist (atomic-bound long pole, VALU 1.8%
// idle) first; gauss (per-edge gaussians -> garr) and gemm backfill the idle
// CUs. Removes the gaussian + 51MB ew read from the post-scan critical path.
// ============================================================================
__global__ __launch_bounds__(256) void histgemm_kernel(
    const float* __restrict__ features, const __half* __restrict__ w12T,
    const int* __restrict__ dst, const float* __restrict__ ew,
    const float* __restrict__ mu1, const float* __restrict__ is1,
    const float* __restrict__ mu2, const float* __restrict__ is2,
    int* __restrict__ counts, unsigned short* __restrict__ rank,
    int* __restrict__ garr, __half* __restrict__ y)
{
    const int tid = threadIdx.x;
    __shared__ __align__(16) __half WT[WCOLS][136];   // W12^T fp16, 13.1 KB

    if (blockIdx.x < HIST_NB) {
        // ---- hist: 4 edges/thread, returning atomics on padded counters ----
        int i = blockIdx.x * 256 + tid;            // quad index
        if (i * 4 >= N_EDGES) return;
        int4 d = ((const int4*)dst)[i];
        ushort4 r;
        r.x = (unsigned short)atomicAdd(&counts[d.x * CNT_STRIDE], 1);
        r.y = (unsigned short)atomicAdd(&counts[d.y * CNT_STRIDE], 1);
        r.z = (unsigned short)atomicAdd(&counts[d.z * CNT_STRIDE], 1);
        r.w = (unsigned short)atomicAdd(&counts[d.w * CNT_STRIDE], 1);
        ((ushort4*)rank)[i] = r;                   // coalesced 8B store
        return;
    }

    if (blockIdx.x < HIST_NB + GAUSS_NB) {
        // ---- gauss: one edge per thread; hides under hist's idle CUs ----
        int e = (blockIdx.x - HIST_NB) * 256 + tid;   // 3125*256 == 800000
        const float4* ew4 = (const float4*)(ew + (size_t)e * DIM);
        float4 wa = ew4[0], wb = ew4[1];
        float v[8] = {wa.x, wa.y, wa.z, wa.w, wb.x, wb.y, wb.z, wb.w};
        float s1 = 0.f, s2 = 0.f;
#pragma unroll
        for (int d = 0; d < DIM; ++d) {
            float d1 = v[d] - mu1[d]; float a1 = is1[d];
            float d2 = v[d] - mu2[d]; float a2 = is2[d];
            s1 += d1 * d1 * a1 * a1;
            s2 += d2 * d2 * a2 * a2;
        }
        __half2 g = __floats2half2_rn(expf(-0.5f * s1), expf(-0.5f * s2));
        garr[e] = *reinterpret_cast<int*>(&g);     // coalesced 4B store
        return;
    }

    // ---- Y-gemm tile: 64 nodes x 48(->40) cols, MFMA 16x16x32 f16 ----
    int nodeBase = (blockIdx.x - HIST_NB - GAUSS_NB) * 64;
    for (int rep = 0; rep < (WCOLS * IN_FEATS) / 256; ++rep) {
        int idx = tid + rep * 256;          // c = idx>>7, k = idx&127
        WT[idx >> 7][idx & 127] = w12T[idx];
    }
    __syncthreads();

    int lane = tid & 63, w = tid >> 6;
    int m = lane & 15, quad = lane >> 4;
    int row = nodeBase + w * 16 + m;
    int rowc = (row < N_NODES) ? row : (N_NODES - 1);
    const float* fr = features + (size_t)rowc * IN_FEATS;

    floatx4 acc0 = {0.f,0.f,0.f,0.f}, acc1 = acc0, acc2 = acc0;
#pragma unroll
    for (int kc = 0; kc < 4; ++kc) {
        float4 fa = *(const float4*)(fr + kc * 32 + quad * 8);
        float4 fb = *(const float4*)(fr + kc * 32 + quad * 8 + 4);
        union { half8 v; __half2 h2[4]; } A;
        A.h2[0] = __floats2half2_rn(fa.x, fa.y);
        A.h2[1] = __floats2half2_rn(fa.z, fa.w);
        A.h2[2] = __floats2half2_rn(fb.x, fb.y);
        A.h2[3] = __floats2half2_rn(fb.z, fb.w);
        half8 b0 = *(const half8*)&WT[ 0 + m][kc * 32 + quad * 8];
        half8 b1 = *(const half8*)&WT[16 + m][kc * 32 + quad * 8];
        half8 b2 = *(const half8*)&WT[32 + m][kc * 32 + quad * 8];
        acc0 = __builtin_amdgcn_mfma_f32_16x16x32_f16(A.v, b0, acc0, 0, 0, 0);
        acc1 = __builtin_amdgcn_mfma_f32_16x16x32_f16(A.v, b1, acc1, 0, 0, 0);
        acc2 = __builtin_amdgcn_mfma_f32_16x16x32_f16(A.v, b2, acc2, 0, 0, 0);
    }
    int nodeRow = nodeBase + w * 16 + quad * 4;
#pragma unroll
    for (int r = 0; r < 4; ++r) {
        int n = nodeRow + r;
        if (n < N_NODES) {
            size_t base = (size_t)n * OUT_FEATS;
            y[base + m]      = __float2half(acc0[r]);
            y[base + m + 16] = __float2half(acc1[r]);
            if (m < 8)
                y[base + m + 32] = __float2half(acc2[r]);
        }
    }
}

// ============================================================================
// K2: single-dispatch decoupled-lookback scan (196 co-resident blocks).
// ============================================================================
__global__ __launch_bounds__(256) void scan_kernel(const int* __restrict__ counts,
                                                   int* __restrict__ offsets,
                                                   int* __restrict__ partials) {
    const int tid = threadIdx.x, bid = blockIdx.x;
    const int i = bid * 256 + tid;
    const int lane = tid & 63, wid = tid >> 6;
    int x = (i < N_NODES) ? counts[i * CNT_STRIDE] : 0;
    int incl = wave_incl_scan(x, lane);
    __shared__ int wsum[4];
    __shared__ int sExc, sTot;
    if (lane == 63) wsum[wid] = incl;
    __syncthreads();
    int base = 0;
#pragma unroll
    for (int w = 0; w < 4; ++w)
        if (w < wid) base += wsum[w];
    int lexcl = base + incl - x;
    if (tid == 255) sTot = base + incl;
    __syncthreads();
    if (tid == 0) {
        int T = sTot;
        if (bid == 0) {
            __hip_atomic_store(&partials[0], (T << 2) | 2,
                               __ATOMIC_RELAXED, __HIP_MEMORY_SCOPE_AGENT);
            sExc = 0;
        } else {
            __hip_atomic_store(&partials[bid], (T << 2) | 1,
                               __ATOMIC_RELAXED, __HIP_MEMORY_SCOPE_AGENT);
            int sum = 0, pb = bid - 1;
            while (true) {
                int v = __hip_atomic_load(&partials[pb],
                                          __ATOMIC_RELAXED, __HIP_MEMORY_SCOPE_AGENT);
                if (v == 0) continue;
                sum += v >> 2;
                if ((v & 3) == 2) break;
                --pb;
            }
            __hip_atomic_store(&partials[bid], ((sum + T) << 2) | 2,
                               __ATOMIC_RELAXED, __HIP_MEMORY_SCOPE_AGENT);
            sExc = sum;
        }
    }
    __syncthreads();
    if (i < N_NODES) offsets[i] = sExc + lexcl;
    if (bid == SCAN_NB - 1 && tid == 0) offsets[N_NODES] = N_EDGES;
}

// ============================================================================
// K3: pure stream+scatter fill: 4 edges/thread, gaussians precomputed (garr).
// pos = offsets[dst] + rank[e]; nontemporal 8B record stores.
// ============================================================================
__global__ __launch_bounds__(256) void fill_kernel(
    const int* __restrict__ src, const int* __restrict__ dst,
    const int* __restrict__ offsets, const unsigned short* __restrict__ rank,
    const int* __restrict__ garr, int2* __restrict__ csr)
{
    int q = blockIdx.x * 256 + threadIdx.x;        // quad index
    if (q * 4 >= N_EDGES) return;
    int4    s4 = ((const int4*)src)[q];
    int4    d4 = ((const int4*)dst)[q];
    ushort4 r4 = ((const ushort4*)rank)[q];
    int4    g4 = ((const int4*)garr)[q];
    int p0 = offsets[d4.x] + r4.x;
    int p1 = offsets[d4.y] + r4.y;
    int p2 = offsets[d4.z] + r4.z;
    int p3 = offsets[d4.w] + r4.w;
    int2 rec0 = make_int2(s4.x, g4.x);
    int2 rec1 = make_int2(s4.y, g4.y);
    int2 rec2 = make_int2(s4.z, g4.z);
    int2 rec3 = make_int2(s4.w, g4.w);
    __builtin_nontemporal_store(*reinterpret_cast<long long*>(&rec0),
                                reinterpret_cast<long long*>(&csr[p0]));
    __builtin_nontemporal_store(*reinterpret_cast<long long*>(&rec1),
                                reinterpret_cast<long long*>(&csr[p1]));
    __builtin_nontemporal_store(*reinterpret_cast<long long*>(&rec2),
                                reinterpret_cast<long long*>(&csr[p2]));
    __builtin_nontemporal_store(*reinterpret_cast<long long*>(&rec3),
                                reinterpret_cast<long long*>(&csr[p3]));
}

// ============================================================================
// agg1 (pure gather): h2[n] = sum_e g1(e) * Y[src(e)] + cvec.
// 2 nodes/wave, 32 lanes/row (20 valid), 8-deep unroll, fp16 dword output.
// ============================================================================
__global__ __launch_bounds__(256) void agg1_kernel(const __half* __restrict__ ysrc,
                                                   const int* __restrict__ offsets,
                                                   const int2* __restrict__ csr,
                                                   const float* __restrict__ cvec,
                                                   __half* __restrict__ h2) {
    const unsigned* h32 = (const unsigned*)ysrc;   // Y row = 20 dwords
    const int tid = threadIdx.x;
    const int w = tid >> 6, lane = tid & 63;
    const int hf = lane >> 5, p = lane & 31;
    const int n = blockIdx.x * 8 + w * 2 + hf;
    const int pc = (p < 20) ? p : 19;           // clamp: no divergence, no OOB
    int beg = offsets[n], end = offsets[n + 1];

    float ax = 0.f, ay = 0.f;
    for (int j = beg; j < end; j += 8) {        // entered only when beg < end
        int j0 = j + 0, j1 = j + 1, j2 = j + 2, j3 = j + 3;
        int j4 = j + 4, j5 = j + 5, j6 = j + 6, j7 = j + 7;
        int e1 = end - 1;
        int2 r0 = csr[(j0 < end) ? j0 : e1];
        int2 r1 = csr[(j1 < end) ? j1 : e1];
        int2 r2 = csr[(j2 < end) ? j2 : e1];
        int2 r3 = csr[(j3 < end) ? j3 : e1];
        int2 r4 = csr[(j4 < end) ? j4 : e1];
        int2 r5 = csr[(j5 < end) ? j5 : e1];
        int2 r6 = csr[(j6 < end) ? j6 : e1];
        int2 r7 = csr[(j7 < end) ? j7 : e1];
        unsigned v0 = h32[(size_t)r0.x * 20 + pc];
        unsigned v1 = h32[(size_t)r1.x * 20 + pc];
        unsigned v2 = h32[(size_t)r2.x * 20 + pc];
        unsigned v3 = h32[(size_t)r3.x * 20 + pc];
        unsigned v4 = h32[(size_t)r4.x * 20 + pc];
        unsigned v5 = h32[(size_t)r5.x * 20 + pc];
        unsigned v6 = h32[(size_t)r6.x * 20 + pc];
        unsigned v7 = h32[(size_t)r7.x * 20 + pc];
        float g0 = (j0 < end) ? __low2float(*reinterpret_cast<__half2*>(&r0.y)) : 0.f;
        float g1 = (j1 < end) ? __low2float(*reinterpret_cast<__half2*>(&r1.y)) : 0.f;
        float g2 = (j2 < end) ? __low2float(*reinterpret_cast<__half2*>(&r2.y)) : 0.f;
        float g3 = (j3 < end) ? __low2float(*reinterpret_cast<__half2*>(&r3.y)) : 0.f;
        float g4 = (j4 < end) ? __low2float(*reinterpret_cast<__half2*>(&r4.y)) : 0.f;
        float g5 = (j5 < end) ? __low2float(*reinterpret_cast<__half2*>(&r5.y)) : 0.f;
        float g6 = (j6 < end) ? __low2float(*reinterpret_cast<__half2*>(&r6.y)) : 0.f;
        float g7 = (j7 < end) ? __low2float(*reinterpret_cast<__half2*>(&r7.y)) : 0.f;
        float2 f0 = __half22float2(*reinterpret_cast<__half2*>(&v0));
        float2 f1 = __half22float2(*reinterpret_cast<__half2*>(&v1));
        float2 f2 = __half22float2(*reinterpret_cast<__half2*>(&v2));
        float2 f3 = __half22float2(*reinterpret_cast<__half2*>(&v3));
        float2 f4 = __half22float2(*reinterpret_cast<__half2*>(&v4));
        float2 f5 = __half22float2(*reinterpret_cast<__half2*>(&v5));
        float2 f6 = __half22float2(*reinterpret_cast<__half2*>(&v6));
        float2 f7 = __half22float2(*reinterpret_cast<__half2*>(&v7));
        ax += f0.x * g0; ay += f0.y * g0;
        ax += f1.x * g1; ay += f1.y * g1;
        ax += f2.x * g2; ay += f2.y * g2;
        ax += f3.x * g3; ay += f3.y * g3;
        ax += f4.x * g4; ay += f4.y * g4;
        ax += f5.x * g5; ay += f5.y * g5;
        ax += f6.x * g6; ay += f6.y * g6;
        ax += f7.x * g7; ay += f7.y * g7;
    }
    if (p < 20) {
        __half2 hv = __floats2half2_rn(ax + cvec[2 * p], ay + cvec[2 * p + 1]);
        ((unsigned*)h2)[(size_t)n * 20 + p] = *reinterpret_cast<unsigned*>(&hv);
    }
}

// ---------------- agg layer 2 + b2 + log_softmax: 8-deep unroll ----------------
__global__ __launch_bounds__(256) void agg2_kernel(const __half* __restrict__ h,
                                                   const int* __restrict__ offsets,
                                                   const int2* __restrict__ csr,
                                                   const float* __restrict__ b,
                                                   float* __restrict__ out) {
    const unsigned* h32 = (const unsigned*)h;   // h2 row = 20 dwords
    const int tid = threadIdx.x;
    const int w = tid >> 6, lane = tid & 63;
    const int hf = lane >> 5, p = lane & 31;
    const int n = blockIdx.x * 8 + w * 2 + hf;
    const int pc = (p < 20) ? p : 19;           // clamp: no divergence, no OOB
    int beg = offsets[n], end = offsets[n + 1];

    float ax = 0.f, ay = 0.f;
    for (int j = beg; j < end; j += 8) {        // entered only when beg < end
        int j0 = j + 0, j1 = j + 1, j2 = j + 2, j3 = j + 3;
        int j4 = j + 4, j5 = j + 5, j6 = j + 6, j7 = j + 7;
        int e1 = end - 1;
        int2 r0 = csr[(j0 < end) ? j0 : e1];
        int2 r1 = csr[(j1 < end) ? j1 : e1];
        int2 r2 = csr[(j2 < end) ? j2 : e1];
        int2 r3 = csr[(j3 < end) ? j3 : e1];
        int2 r4 = csr[(j4 < end) ? j4 : e1];
        int2 r5 = csr[(j5 < end) ? j5 : e1];
        int2 r6 = csr[(j6 < end) ? j6 : e1];
        int2 r7 = csr[(j7 < end) ? j7 : e1];
        unsigned v0 = h32[(size_t)r0.x * 20 + pc];
        unsigned v1 = h32[(size_t)r1.x * 20 + pc];
        unsigned v2 = h32[(size_t)r2.x * 20 + pc];
        unsigned v3 = h32[(size_t)r3.x * 20 + pc];
        unsigned v4 = h32[(size_t)r4.x * 20 + pc];
        unsigned v5 = h32[(size_t)r5.x * 20 + pc];
        unsigned v6 = h32[(size_t)r6.x * 20 + pc];
        unsigned v7 = h32[(size_t)r7.x * 20 + pc];
        float g0 = (j0 < end) ? __high2float(*reinterpret_cast<__half2*>(&r0.y)) : 0.f;
        float g1 = (j1 < end) ? __high2float(*reinterpret_cast<__half2*>(&r1.y)) : 0.f;
        float g2 = (j2 < end) ? __high2float(*reinterpret_cast<__half2*>(&r2.y)) : 0.f;
        float g3 = (j3 < end) ? __high2float(*reinterpret_cast<__half2*>(&r3.y)) : 0.f;
        float g4 = (j4 < end) ? __high2float(*reinterpret_cast<__half2*>(&r4.y)) : 0.f;
        float g5 = (j5 < end) ? __high2float(*reinterpret_cast<__half2*>(&r5.y)) : 0.f;
        float g6 = (j6 < end) ? __high2float(*reinterpret_cast<__half2*>(&r6.y)) : 0.f;
        float g7 = (j7 < end) ? __high2float(*reinterpret_cast<__half2*>(&r7.y)) : 0.f;
        float2 f0 = __half22float2(*reinterpret_cast<__half2*>(&v0));
        float2 f1 = __half22float2(*reinterpret_cast<__half2*>(&v1));
        float2 f2 = __half22float2(*reinterpret_cast<__half2*>(&v2));
        float2 f3 = __half22float2(*reinterpret_cast<__half2*>(&v3));
        float2 f4 = __half22float2(*reinterpret_cast<__half2*>(&v4));
        float2 f5 = __half22float2(*reinterpret_cast<__half2*>(&v5));
        float2 f6 = __half22float2(*reinterpret_cast<__half2*>(&v6));
        float2 f7 = __half22float2(*reinterpret_cast<__half2*>(&v7));
        ax += f0.x * g0; ay += f0.y * g0;
        ax += f1.x * g1; ay += f1.y * g1;
        ax += f2.x * g2; ay += f2.y * g2;
        ax += f3.x * g3; ay += f3.y * g3;
        ax += f4.x * g4; ay += f4.y * g4;
        ax += f5.x * g5; ay += f5.y * g5;
        ax += f6.x * g6; ay += f6.y * g6;
        ax += f7.x * g7; ay += f7.y * g7;
    }

    bool valid = (p < 20);
    float vx = valid ? ax + b[2 * p]     : -INFINITY;
    float vy = valid ? ay + b[2 * p + 1] : -INFINITY;
    float m = fmaxf(vx, vy);
#pragma unroll
    for (int off = 16; off; off >>= 1)
        m = fmaxf(m, __shfl_xor(m, off, 32));   // reduce within each 32-lane half
    float ex = valid ? (expf(vx - m) + expf(vy - m)) : 0.f;
#pragma unroll
    for (int off = 16; off; off >>= 1)
        ex += __shfl_xor(ex, off, 32);
    float ls = logf(ex);
    if (valid) {
        float2 o = make_float2(vx - m - ls, vy - m - ls);
        *(float2*)&out[(size_t)n * OUT_FEATS + 2 * p] = o;
    }
}

extern "C" void kernel_launch(void* const* d_in, const int* in_sizes, int n_in,
                              void* d_out, int out_size, void* d_ws, size_t ws_size,
                              hipStream_t stream) {
    const float* features    = (const float*)d_in[0];
    const float* edge_weight = (const float*)d_in[1];
    const int*   src         = (const int*)d_in[2];
    const int*   dst         = (const int*)d_in[3];
    const float* W1          = (const float*)d_in[4];
    const float* b1          = (const float*)d_in[5];
    const float* mu1         = (const float*)d_in[6];
    const float* is1         = (const float*)d_in[7];
    const float* W2          = (const float*)d_in[8];
    const float* b2          = (const float*)d_in[9];
    const float* mu2         = (const float*)d_in[10];
    const float* is2         = (const float*)d_in[11];
    float* out = (float*)d_out;

    // Workspace: csr int2[800k] 6.4M | Y half[2M] 4M | h2 half[2M] 4M
    //            | counts[50k*4 padded] 800K | rank u16[800k] 1.6M
    //            | offsets[50k+1] 200K | partials[256] 1K
    //            | w12T half[48*128] 12.3K | cvec f32[64 pad]
    //            | garr int[800k] 3.2M                              (~20.3 MB)
    int2*           csr     = (int2*)d_ws;
    __half*         Y       = (__half*)(csr + N_EDGES);
    __half*         h2      = Y + (size_t)N_NODES * OUT_FEATS;
    int*            counts  = (int*)(h2 + (size_t)N_NODES * OUT_FEATS);
    unsigned short* rank    = (unsigned short*)(counts + N_NODES * CNT_STRIDE);
    int*            offsets = (int*)(rank + N_EDGES);
    int*            partials= offsets + N_NODES + 1;
    __half*         w12T    = (__half*)(partials + 256);
    float*          cvec    = (float*)(w12T + WCOLS * IN_FEATS);
    int*            garr    = (int*)(cvec + 64);

    // 6 dispatches: w12(+zeroing) -> histgemm(+gauss) -> scan(lookback)
    // -> fill(stream+scatter) -> agg1 -> agg2
    w12_kernel<<<W12_NB, 256, 0, stream>>>(W1, W2, b1, w12T, cvec, counts, partials);

    histgemm_kernel<<<HIST_NB + GAUSS_NB + GT_TILES, 256, 0, stream>>>(
        features, w12T, dst, edge_weight, mu1, is1, mu2, is2,
        counts, rank, garr, Y);

    scan_kernel<<<SCAN_NB, 256, 0, stream>>>(counts, offsets, partials);

    fill_kernel<<<FILLQ_NB, 256, 0, stream>>>(src, dst, offsets, rank, garr, csr);

    agg1_kernel<<<N_NODES / 8, 256, 0, stream>>>(Y, offsets, csr, cvec, h2);

    agg2_kernel<<<N_NODES / 8, 256, 0, stream>>>(h2, offsets, csr, b2, out);
}

// Round 13
// 224.848 us; speedup vs baseline: 1.0656x; 1.0656x over previous
//
#include <hip/hip_runtime.h>
#include <hip/hip_fp16.h>
#include <math.h>

#define N_NODES 50000
#define N_EDGES 800000
#define IN_FEATS 128
#define N_HIDDEN 64
#define OUT_FEATS 40
#define DIM 8
#define GT_TILES ((N_NODES + 63) / 64)            // 782 gemm tiles
#define HIST_NB ((N_EDGES / 4 + 255) / 256)       // 782 hist blocks
#define FILL_BLOCKS (N_EDGES / 256)               // 3125 fill blocks, 1 edge/thread
#define SCAN_NB ((N_NODES + 255) / 256)           // 196 scan blocks
#define CNT_STRIDE 4                               // counts padded to 16B/counter
#define WCOLS 48                                   // W12 cols padded 40 -> 48
#define W12_NB ((WCOLS * IN_FEATS) / 256)          // 24 blocks: one thread/element

typedef _Float16 half8 __attribute__((ext_vector_type(8)));
typedef float floatx4 __attribute__((ext_vector_type(4)));

// ---------------- wave-wide inclusive scan (64 lanes) ----------------
__device__ __forceinline__ int wave_incl_scan(int x, int lane) {
#pragma unroll
    for (int off = 1; off < 64; off <<= 1) {
        int v = __shfl_up(x, off, 64);
        if (lane >= off) x += v;
    }
    return x;
}

// ============================================================================
// K0: W12 = W1 @ W2 (fp16, transposed [48][128] zero-padded), 24 blocks.
// cvec = b1 @ W2 by block 0's first 40 threads.
// ============================================================================
__global__ __launch_bounds__(256) void w12_kernel(const float* __restrict__ W1,
                                                  const float* __restrict__ W2,
                                                  const float* __restrict__ b1,
                                                  __half* __restrict__ w12T,
                                                  float* __restrict__ cvec) {
    const int idx = blockIdx.x * 256 + threadIdx.x;   // < WCOLS*IN_FEATS
    const int c = idx >> 7;              // 0..47 (out col)
    const int i = idx & 127;             // input feat
    float s = 0.f;
    if (c < OUT_FEATS) {
#pragma unroll 8
        for (int k = 0; k < N_HIDDEN; ++k)
            s += W1[i * N_HIDDEN + k] * W2[k * OUT_FEATS + c];
    }
    w12T[idx] = __float2half(s);         // w12T[c][i]
    if (idx < OUT_FEATS) {
        float t = 0.f;
        for (int k = 0; k < N_HIDDEN; ++k)
            t += b1[k] * W2[k * OUT_FEATS + idx];
        cvec[idx] = t;
    }
}

// ============================================================================
// K1: MERGED hist + Y-gemm. Hist half is atomic-throughput-bound (~45 RMW/cy
// chip-wide at 800k returning atomics) -- near its floor; gemm hides under it.
// (R12 showed adding MORE work (gauss) does NOT hide: L2 fabric contention.)
// ============================================================================
__global__ __launch_bounds__(256) void histgemm_kernel(
    const float* __restrict__ features, const __half* __restrict__ w12T,
    const int* __restrict__ dst,
    int* __restrict__ counts, unsigned short* __restrict__ rank,
    __half* __restrict__ y)
{
    const int tid = threadIdx.x;
    __shared__ __align__(16) __half WT[WCOLS][136];   // W12^T fp16, 13.1 KB

    if (blockIdx.x < HIST_NB) {
        // ---- hist: 4 edges/thread, returning atomics on padded counters ----
        int i = blockIdx.x * 256 + tid;            // quad index
        if (i * 4 >= N_EDGES) return;
        int4 d = ((const int4*)dst)[i];
        ushort4 r;
        r.x = (unsigned short)atomicAdd(&counts[d.x * CNT_STRIDE], 1);
        r.y = (unsigned short)atomicAdd(&counts[d.y * CNT_STRIDE], 1);
        r.z = (unsigned short)atomicAdd(&counts[d.z * CNT_STRIDE], 1);
        r.w = (unsigned short)atomicAdd(&counts[d.w * CNT_STRIDE], 1);
        ((ushort4*)rank)[i] = r;                   // coalesced 8B store
        return;
    }

    // ---- Y-gemm tile: 64 nodes x 48(->40) cols, MFMA 16x16x32 f16 ----
    int nodeBase = (blockIdx.x - HIST_NB) * 64;
    for (int rep = 0; rep < (WCOLS * IN_FEATS) / 256; ++rep) {
        int idx = tid + rep * 256;          // c = idx>>7, k = idx&127
        WT[idx >> 7][idx & 127] = w12T[idx];
    }
    __syncthreads();

    int lane = tid & 63, w = tid >> 6;
    int m = lane & 15, quad = lane >> 4;
    int row = nodeBase + w * 16 + m;
    int rowc = (row < N_NODES) ? row : (N_NODES - 1);
    const float* fr = features + (size_t)rowc * IN_FEATS;

    floatx4 acc0 = {0.f,0.f,0.f,0.f}, acc1 = acc0, acc2 = acc0;
#pragma unroll
    for (int kc = 0; kc < 4; ++kc) {
        float4 fa = *(const float4*)(fr + kc * 32 + quad * 8);
        float4 fb = *(const float4*)(fr + kc * 32 + quad * 8 + 4);
        union { half8 v; __half2 h2[4]; } A;
        A.h2[0] = __floats2half2_rn(fa.x, fa.y);
        A.h2[1] = __floats2half2_rn(fa.z, fa.w);
        A.h2[2] = __floats2half2_rn(fb.x, fb.y);
        A.h2[3] = __floats2half2_rn(fb.z, fb.w);
        half8 b0 = *(const half8*)&WT[ 0 + m][kc * 32 + quad * 8];
        half8 b1 = *(const half8*)&WT[16 + m][kc * 32 + quad * 8];
        half8 b2 = *(const half8*)&WT[32 + m][kc * 32 + quad * 8];
        acc0 = __builtin_amdgcn_mfma_f32_16x16x32_f16(A.v, b0, acc0, 0, 0, 0);
        acc1 = __builtin_amdgcn_mfma_f32_16x16x32_f16(A.v, b1, acc1, 0, 0, 0);
        acc2 = __builtin_amdgcn_mfma_f32_16x16x32_f16(A.v, b2, acc2, 0, 0, 0);
    }
    int nodeRow = nodeBase + w * 16 + quad * 4;
#pragma unroll
    for (int r = 0; r < 4; ++r) {
        int n = nodeRow + r;
        if (n < N_NODES) {
            size_t base = (size_t)n * OUT_FEATS;
            y[base + m]      = __float2half(acc0[r]);
            y[base + m + 16] = __float2half(acc1[r]);
            if (m < 8)
                y[base + m + 32] = __float2half(acc2[r]);
        }
    }
}

// ============================================================================
// K2a/b/c: hierarchical scan over the PADDED counts array.
// ============================================================================
__global__ __launch_bounds__(256) void scan_partial_kernel(const int* __restrict__ counts,
                                                           int* __restrict__ offsets,
                                                           int* __restrict__ partials) {
    const int tid = threadIdx.x, bid = blockIdx.x;
    const int i = bid * 256 + tid;
    const int lane = tid & 63, wid = tid >> 6;
    int x = (i < N_NODES) ? counts[i * CNT_STRIDE] : 0;
    int incl = wave_incl_scan(x, lane);
    __shared__ int wsum[4];
    if (lane == 63) wsum[wid] = incl;
    __syncthreads();
    int base = 0;
#pragma unroll
    for (int w = 0; w < 4; ++w)
        if (w < wid) base += wsum[w];
    if (i < N_NODES) offsets[i] = base + incl - x;   // block-local exclusive
    if (tid == 255) partials[bid] = base + incl;     // block total
}

__global__ __launch_bounds__(256) void scan_base_kernel(int* __restrict__ partials) {
    const int tid = threadIdx.x;
    const int lane = tid & 63, wid = tid >> 6;
    int x = (tid < SCAN_NB) ? partials[tid] : 0;
    int incl = wave_incl_scan(x, lane);
    __shared__ int wsum[4];
    if (lane == 63) wsum[wid] = incl;
    __syncthreads();
    int base = 0;
#pragma unroll
    for (int w = 0; w < 4; ++w)
        if (w < wid) base += wsum[w];
    if (tid < SCAN_NB) partials[tid] = base + incl - x;  // exclusive base per block
}

__global__ __launch_bounds__(256) void scan_add_kernel(int* __restrict__ offsets,
                                                       const int* __restrict__ partials) {
    const int i = blockIdx.x * 256 + threadIdx.x;
    if (i < N_NODES) offsets[i] += partials[blockIdx.x];
    if (i == N_NODES) offsets[N_NODES] = N_EDGES;    // block 195 covers i==50000
}

// ============================================================================
// K3: ATOMIC-FREE CSR fill (pos = offsets[dst] + rank[e]), gaussian inline.
// ============================================================================
__global__ __launch_bounds__(256) void fill_kernel(
    const int* __restrict__ src, const int* __restrict__ dst,
    const float* __restrict__ ew,
    const float* __restrict__ mu1, const float* __restrict__ is1,
    const float* __restrict__ mu2, const float* __restrict__ is2,
    const int* __restrict__ offsets, const unsigned short* __restrict__ rank,
    int2* __restrict__ csr)
{
    int e = blockIdx.x * 256 + threadIdx.x;        // 3125*256 == 800000 exactly
    int sN = src[e];
    int dN = dst[e];
    unsigned short rk = rank[e];
    const float4* ew4 = (const float4*)(ew + (size_t)e * DIM);
    float4 wa = ew4[0], wb = ew4[1];
    float v[8] = {wa.x, wa.y, wa.z, wa.w, wb.x, wb.y, wb.z, wb.w};
    float s1 = 0.f, s2 = 0.f;
#pragma unroll
    for (int d = 0; d < DIM; ++d) {
        float d1 = v[d] - mu1[d]; float a1 = is1[d];
        float d2 = v[d] - mu2[d]; float a2 = is2[d];
        s1 += d1 * d1 * a1 * a1;
        s2 += d2 * d2 * a2 * a2;
    }
    __half2 g = __floats2half2_rn(expf(-0.5f * s1), expf(-0.5f * s2));
    int2 rec;
    rec.x = sN;
    rec.y = *reinterpret_cast<int*>(&g);
    int pos = offsets[dN] + rk;                    // offsets: 200KB, L2-hot
    __builtin_nontemporal_store(*reinterpret_cast<long long*>(&rec),
                                reinterpret_cast<long long*>(&csr[pos]));
}

// ============================================================================
// agg1 (pure gather): h2[n] = sum_e g1(e) * Y[src(e)] + cvec.
// 2 nodes/wave, 32 lanes/row (20 valid), 8-deep unroll, fp16 dword output.
// ============================================================================
__global__ __launch_bounds__(256) void agg1_kernel(const __half* __restrict__ ysrc,
                                                   const int* __restrict__ offsets,
                                                   const int2* __restrict__ csr,
                                                   const float* __restrict__ cvec,
                                                   __half* __restrict__ h2) {
    const unsigned* h32 = (const unsigned*)ysrc;   // Y row = 20 dwords
    const int tid = threadIdx.x;
    const int w = tid >> 6, lane = tid & 63;
    const int hf = lane >> 5, p = lane & 31;
    const int n = blockIdx.x * 8 + w * 2 + hf;
    const int pc = (p < 20) ? p : 19;           // clamp: no divergence, no OOB
    int beg = offsets[n], end = offsets[n + 1];

    float ax = 0.f, ay = 0.f;
    for (int j = beg; j < end; j += 8) {        // entered only when beg < end
        int j0 = j + 0, j1 = j + 1, j2 = j + 2, j3 = j + 3;
        int j4 = j + 4, j5 = j + 5, j6 = j + 6, j7 = j + 7;
        int e1 = end - 1;
        int2 r0 = csr[(j0 < end) ? j0 : e1];
        int2 r1 = csr[(j1 < end) ? j1 : e1];
        int2 r2 = csr[(j2 < end) ? j2 : e1];
        int2 r3 = csr[(j3 < end) ? j3 : e1];
        int2 r4 = csr[(j4 < end) ? j4 : e1];
        int2 r5 = csr[(j5 < end) ? j5 : e1];
        int2 r6 = csr[(j6 < end) ? j6 : e1];
        int2 r7 = csr[(j7 < end) ? j7 : e1];
        unsigned v0 = h32[(size_t)r0.x * 20 + pc];
        unsigned v1 = h32[(size_t)r1.x * 20 + pc];
        unsigned v2 = h32[(size_t)r2.x * 20 + pc];
        unsigned v3 = h32[(size_t)r3.x * 20 + pc];
        unsigned v4 = h32[(size_t)r4.x * 20 + pc];
        unsigned v5 = h32[(size_t)r5.x * 20 + pc];
        unsigned v6 = h32[(size_t)r6.x * 20 + pc];
        unsigned v7 = h32[(size_t)r7.x * 20 + pc];
        float g0 = (j0 < end) ? __low2float(*reinterpret_cast<__half2*>(&r0.y)) : 0.f;
        float g1 = (j1 < end) ? __low2float(*reinterpret_cast<__half2*>(&r1.y)) : 0.f;
        float g2 = (j2 < end) ? __low2float(*reinterpret_cast<__half2*>(&r2.y)) : 0.f;
        float g3 = (j3 < end) ? __low2float(*reinterpret_cast<__half2*>(&r3.y)) : 0.f;
        float g4 = (j4 < end) ? __low2float(*reinterpret_cast<__half2*>(&r4.y)) : 0.f;
        float g5 = (j5 < end) ? __low2float(*reinterpret_cast<__half2*>(&r5.y)) : 0.f;
        float g6 = (j6 < end) ? __low2float(*reinterpret_cast<__half2*>(&r6.y)) : 0.f;
        float g7 = (j7 < end) ? __low2float(*reinterpret_cast<__half2*>(&r7.y)) : 0.f;
        float2 f0 = __half22float2(*reinterpret_cast<__half2*>(&v0));
        float2 f1 = __half22float2(*reinterpret_cast<__half2*>(&v1));
        float2 f2 = __half22float2(*reinterpret_cast<__half2*>(&v2));
        float2 f3 = __half22float2(*reinterpret_cast<__half2*>(&v3));
        float2 f4 = __half22float2(*reinterpret_cast<__half2*>(&v4));
        float2 f5 = __half22float2(*reinterpret_cast<__half2*>(&v5));
        float2 f6 = __half22float2(*reinterpret_cast<__half2*>(&v6));
        float2 f7 = __half22float2(*reinterpret_cast<__half2*>(&v7));
        ax += f0.x * g0; ay += f0.y * g0;
        ax += f1.x * g1; ay += f1.y * g1;
        ax += f2.x * g2; ay += f2.y * g2;
        ax += f3.x * g3; ay += f3.y * g3;
        ax += f4.x * g4; ay += f4.y * g4;
        ax += f5.x * g5; ay += f5.y * g5;
        ax += f6.x * g6; ay += f6.y * g6;
        ax += f7.x * g7; ay += f7.y * g7;
    }
    if (p < 20) {
        __half2 hv = __floats2half2_rn(ax + cvec[2 * p], ay + cvec[2 * p + 1]);
        ((unsigned*)h2)[(size_t)n * 20 + p] = *reinterpret_cast<unsigned*>(&hv);
    }
}

// ---------------- agg layer 2 + b2 + log_softmax: 8-deep unroll ----------------
__global__ __launch_bounds__(256) void agg2_kernel(const __half* __restrict__ h,
                                                   const int* __restrict__ offsets,
                                                   const int2* __restrict__ csr,
                                                   const float* __restrict__ b,
                                                   float* __restrict__ out) {
    const unsigned* h32 = (const unsigned*)h;   // h2 row = 20 dwords
    const int tid = threadIdx.x;
    const int w = tid >> 6, lane = tid & 63;
    const int hf = lane >> 5, p = lane & 31;
    const int n = blockIdx.x * 8 + w * 2 + hf;
    const int pc = (p < 20) ? p : 19;           // clamp: no divergence, no OOB
    int beg = offsets[n], end = offsets[n + 1];

    float ax = 0.f, ay = 0.f;
    for (int j = beg; j < end; j += 8) {        // entered only when beg < end
        int j0 = j + 0, j1 = j + 1, j2 = j + 2, j3 = j + 3;
        int j4 = j + 4, j5 = j + 5, j6 = j + 6, j7 = j + 7;
        int e1 = end - 1;
        int2 r0 = csr[(j0 < end) ? j0 : e1];
        int2 r1 = csr[(j1 < end) ? j1 : e1];
        int2 r2 = csr[(j2 < end) ? j2 : e1];
        int2 r3 = csr[(j3 < end) ? j3 : e1];
        int2 r4 = csr[(j4 < end) ? j4 : e1];
        int2 r5 = csr[(j5 < end) ? j5 : e1];
        int2 r6 = csr[(j6 < end) ? j6 : e1];
        int2 r7 = csr[(j7 < end) ? j7 : e1];
        unsigned v0 = h32[(size_t)r0.x * 20 + pc];
        unsigned v1 = h32[(size_t)r1.x * 20 + pc];
        unsigned v2 = h32[(size_t)r2.x * 20 + pc];
        unsigned v3 = h32[(size_t)r3.x * 20 + pc];
        unsigned v4 = h32[(size_t)r4.x * 20 + pc];
        unsigned v5 = h32[(size_t)r5.x * 20 + pc];
        unsigned v6 = h32[(size_t)r6.x * 20 + pc];
        unsigned v7 = h32[(size_t)r7.x * 20 + pc];
        float g0 = (j0 < end) ? __high2float(*reinterpret_cast<__half2*>(&r0.y)) : 0.f;
        float g1 = (j1 < end) ? __high2float(*reinterpret_cast<__half2*>(&r1.y)) : 0.f;
        float g2 = (j2 < end) ? __high2float(*reinterpret_cast<__half2*>(&r2.y)) : 0.f;
        float g3 = (j3 < end) ? __high2float(*reinterpret_cast<__half2*>(&r3.y)) : 0.f;
        float g4 = (j4 < end) ? __high2float(*reinterpret_cast<__half2*>(&r4.y)) : 0.f;
        float g5 = (j5 < end) ? __high2float(*reinterpret_cast<__half2*>(&r5.y)) : 0.f;
        float g6 = (j6 < end) ? __high2float(*reinterpret_cast<__half2*>(&r6.y)) : 0.f;
        float g7 = (j7 < end) ? __high2float(*reinterpret_cast<__half2*>(&r7.y)) : 0.f;
        float2 f0 = __half22float2(*reinterpret_cast<__half2*>(&v0));
        float2 f1 = __half22float2(*reinterpret_cast<__half2*>(&v1));
        float2 f2 = __half22float2(*reinterpret_cast<__half2*>(&v2));
        float2 f3 = __half22float2(*reinterpret_cast<__half2*>(&v3));
        float2 f4 = __half22float2(*reinterpret_cast<__half2*>(&v4));
        float2 f5 = __half22float2(*reinterpret_cast<__half2*>(&v5));
        float2 f6 = __half22float2(*reinterpret_cast<__half2*>(&v6));
        float2 f7 = __half22float2(*reinterpret_cast<__half2*>(&v7));
        ax += f0.x * g0; ay += f0.y * g0;
        ax += f1.x * g1; ay += f1.y * g1;
        ax += f2.x * g2; ay += f2.y * g2;
        ax += f3.x * g3; ay += f3.y * g3;
        ax += f4.x * g4; ay += f4.y * g4;
        ax += f5.x * g5; ay += f5.y * g5;
        ax += f6.x * g6; ay += f6.y * g6;
        ax += f7.x * g7; ay += f7.y * g7;
    }

    bool valid = (p < 20);
    float vx = valid ? ax + b[2 * p]     : -INFINITY;
    float vy = valid ? ay + b[2 * p + 1] : -INFINITY;
    float m = fmaxf(vx, vy);
#pragma unroll
    for (int off = 16; off; off >>= 1)
        m = fmaxf(m, __shfl_xor(m, off, 32));   // reduce within each 32-lane half
    float ex = valid ? (expf(vx - m) + expf(vy - m)) : 0.f;
#pragma unroll
    for (int off = 16; off; off >>= 1)
        ex += __shfl_xor(ex, off, 32);
    float ls = logf(ex);
    if (valid) {
        float2 o = make_float2(vx - m - ls, vy - m - ls);
        *(float2*)&out[(size_t)n * OUT_FEATS + 2 * p] = o;
    }
}

extern "C" void kernel_launch(void* const* d_in, const int* in_sizes, int n_in,
                              void* d_out, int out_size, void* d_ws, size_t ws_size,
                              hipStream_t stream) {
    const float* features    = (const float*)d_in[0];
    const float* edge_weight = (const float*)d_in[1];
    const int*   src         = (const int*)d_in[2];
    const int*   dst         = (const int*)d_in[3];
    const float* W1          = (const float*)d_in[4];
    const float* b1          = (const float*)d_in[5];
    const float* mu1         = (const float*)d_in[6];
    const float* is1         = (const float*)d_in[7];
    const float* W2          = (const float*)d_in[8];
    const float* b2          = (const float*)d_in[9];
    const float* mu2         = (const float*)d_in[10];
    const float* is2         = (const float*)d_in[11];
    float* out = (float*)d_out;

    // Workspace: csr int2[800k] 6.4M | Y half[2M] 4M | h2 half[2M] 4M
    //            | counts[50k*4 padded] 800K | rank u16[800k] 1.6M
    //            | offsets[50k+1] 200K | partials[256] 1K
    //            | w12T half[48*128] 12.3K | cvec f32[40]           (~17 MB)
    int2*           csr     = (int2*)d_ws;
    __half*         Y       = (__half*)(csr + N_EDGES);
    __half*         h2      = Y + (size_t)N_NODES * OUT_FEATS;
    int*            counts  = (int*)(h2 + (size_t)N_NODES * OUT_FEATS);
    unsigned short* rank    = (unsigned short*)(counts + N_NODES * CNT_STRIDE);
    int*            offsets = (int*)(rank + N_EDGES);
    int*            partials= offsets + N_NODES + 1;
    __half*         w12T    = (__half*)(partials + 256);
    float*          cvec    = (float*)(w12T + WCOLS * IN_FEATS);

    hipMemsetAsync(counts, 0, (size_t)N_NODES * CNT_STRIDE * sizeof(int), stream);

    w12_kernel<<<W12_NB, 256, 0, stream>>>(W1, W2, b1, w12T, cvec);

    histgemm_kernel<<<HIST_NB + GT_TILES, 256, 0, stream>>>(
        features, w12T, dst, counts, rank, Y);

    scan_partial_kernel<<<SCAN_NB, 256, 0, stream>>>(counts, offsets, partials);
    scan_base_kernel<<<1, 256, 0, stream>>>(partials);
    scan_add_kernel<<<SCAN_NB, 256, 0, stream>>>(offsets, partials);

    fill_kernel<<<FILL_BLOCKS, 256, 0, stream>>>(
        src, dst, edge_weight, mu1, is1, mu2, is2, offsets, rank, csr);

    agg1_kernel<<<N_NODES / 8, 256, 0, stream>>>(Y, offsets, csr, cvec, h2);

    agg2_kernel<<<N_NODES / 8, 256, 0, stream>>>(h2, offsets, csr, b2, out);
}